// Round 6
// baseline (226.683 us; speedup 1.0000x reference)
//
#include <hip/hip_runtime.h>

// DAG MLP: L=8 layers, D=64, B=262144, 28 all-to-all forward connections.
// outs[j] += relu(outs[i] @ W_c^T + b_c), output = outs[7].
// v6: BARRIER-FREE. Weights are read directly global->VGPR from a linear bf16
// image (L2-resident, 229 KB), ping-pong register buffer prefetched one
// connection ahead. No LDS ring, no __syncthreads anywhere: every wave is an
// independent stream (32 rows/wave, activations register-resident as bf16 MFMA
// A-fragments). LDS only for the wave-private D->A bounce (2 KB/wave).
// Accumulation rides the MFMA C operand: C_in=acc; acc=max(D+bias, acc)
// == acc + relu(S + bias)  (exact in f32).

#define DD 64
#define NCONN 28
#define THREADS 256
#define ROWS_PER_WAVE 32
#define ROWS_PER_BLOCK 128     // 4 waves * 32 rows
#define MAT_ELEMS 4096         // 64*64

typedef __bf16 bf16x8 __attribute__((ext_vector_type(8)));
typedef float f32x4 __attribute__((ext_vector_type(4)));
typedef unsigned short u16x8 __attribute__((ext_vector_type(8)));

// c(i->j) = OFFS[i] + (j-i-1); CONN[p] = connection at compute position p
// (phases j=1..7, sources i ascending within phase).
__device__ constexpr int OFFS[7] = {0, 7, 13, 18, 22, 25, 27};
__device__ constexpr int CONN[28] = {0, 1,7, 2,8,13, 3,9,14,18, 4,10,15,19,22,
                                     5,11,16,20,23,25, 6,12,17,21,24,26,27};

__device__ __forceinline__ unsigned short f2bfu(float f) {
    return __builtin_bit_cast(unsigned short, (__bf16)f);
}

__device__ __forceinline__ f32x4 vmax4(f32x4 a, f32x4 b) {
#if __has_builtin(__builtin_elementwise_max)
    return __builtin_elementwise_max(a, b);
#else
    f32x4 r;
    r[0] = fmaxf(a[0], b[0]); r[1] = fmaxf(a[1], b[1]);
    r[2] = fmaxf(a[2], b[2]); r[3] = fmaxf(a[3], b[3]);
    return r;
#endif
}

// fp32 W -> bf16 LINEAR image in d_ws (no swizzle; consumed by VGPR loads).
__global__ void wconv_kernel(const float* __restrict__ w,
                             unsigned short* __restrict__ o) {
    int i = blockIdx.x * blockDim.x + threadIdx.x;   // one 8-elem chunk each
    if (i >= NCONN * 512) return;
    const float* src = w + i * 8;
    float4 v0 = *reinterpret_cast<const float4*>(src);
    float4 v1 = *reinterpret_cast<const float4*>(src + 4);
    u16x8 d;
    d[0] = f2bfu(v0.x); d[1] = f2bfu(v0.y); d[2] = f2bfu(v0.z); d[3] = f2bfu(v0.w);
    d[4] = f2bfu(v1.x); d[5] = f2bfu(v1.y); d[6] = f2bfu(v1.z); d[7] = f2bfu(v1.w);
    *reinterpret_cast<u16x8*>(o + i * 8) = d;
}

template <bool BF16IMG>
__global__ __launch_bounds__(THREADS, 2)
void dag_kernel(const float* __restrict__ x,
                const float* __restrict__ Wf,
                const unsigned short* __restrict__ Wimg,
                const float* __restrict__ bs,
                float* __restrict__ out) {
    __shared__ __align__(16) unsigned short sB[4 * 1024];   // 8 KB: 2 KB/wave bounce

    const int tid  = threadIdx.x;
    const int lane = tid & 63;
    const int wv   = tid >> 6;
    const int l15  = lane & 15;
    const int kg   = lane >> 4;

    const long rowbase = (long)blockIdx.x * ROWS_PER_BLOCK + wv * ROWS_PER_WAVE;

    // ---- x -> afrag[0] ----
    bf16x8 afrag[7][2][2];   // [src layer][rowtile][kstep]
#pragma unroll
    for (int rt = 0; rt < 2; ++rt) {
        const float* xr = x + (rowbase + rt * 16 + l15) * DD;
#pragma unroll
        for (int s = 0; s < 2; ++s) {
            float4 v0 = *reinterpret_cast<const float4*>(xr + s * 32 + kg * 8);
            float4 v1 = *reinterpret_cast<const float4*>(xr + s * 32 + kg * 8 + 4);
            bf16x8 f;
            f[0] = (__bf16)v0.x; f[1] = (__bf16)v0.y; f[2] = (__bf16)v0.z; f[3] = (__bf16)v0.w;
            f[4] = (__bf16)v1.x; f[5] = (__bf16)v1.y; f[6] = (__bf16)v1.z; f[7] = (__bf16)v1.w;
            afrag[0][rt][s] = f;
        }
    }

    // W B-fragment register buffers, ping-pong across connections.
    // wbuf[b][t*2+s]: lane holds W[t*16+l15][s*32+kg*8 .. +7] of the buffered conn.
    u16x8 wbufA[8], wbufB[8];

    auto loadW = [&](int p, u16x8* dst) {
        if constexpr (BF16IMG) {
            const unsigned short* base = Wimg + CONN[p] * MAT_ELEMS + l15 * DD + kg * 8;
#pragma unroll
            for (int t = 0; t < 4; ++t)
#pragma unroll
                for (int s = 0; s < 2; ++s)
                    dst[t * 2 + s] = *reinterpret_cast<const u16x8*>(
                        base + t * 16 * DD + s * 32);
        } else {
            const float* base = Wf + CONN[p] * MAT_ELEMS + l15 * DD + kg * 8;
#pragma unroll
            for (int t = 0; t < 4; ++t)
#pragma unroll
                for (int s = 0; s < 2; ++s) {
                    float4 v0 = *reinterpret_cast<const float4*>(base + t * 16 * DD + s * 32);
                    float4 v1 = *reinterpret_cast<const float4*>(base + t * 16 * DD + s * 32 + 4);
                    u16x8 d;
                    d[0] = f2bfu(v0.x); d[1] = f2bfu(v0.y); d[2] = f2bfu(v0.z); d[3] = f2bfu(v0.w);
                    d[4] = f2bfu(v1.x); d[5] = f2bfu(v1.y); d[6] = f2bfu(v1.z); d[7] = f2bfu(v1.w);
                    dst[t * 2 + s] = d;
                }
        }
    };

    loadW(0, wbufA);   // prologue prefetch

    unsigned short* myB = sB + wv * 1024;
    f32x4 acc[2][4];

#pragma unroll
    for (int j = 1; j <= 7; ++j) {
#pragma unroll
        for (int rt = 0; rt < 2; ++rt)
#pragma unroll
            for (int t = 0; t < 4; ++t) {
                acc[rt][t][0] = 0.f; acc[rt][t][1] = 0.f;
                acc[rt][t][2] = 0.f; acc[rt][t][3] = 0.f;
            }

#pragma unroll
        for (int i = 0; i < j; ++i) {
            const int p = j * (j - 1) / 2 + i;      // compute position 0..27 (constexpr)
            const int c = OFFS[i] + (j - i - 1);    // connection index
            u16x8* wcur = (p & 1) ? wbufB : wbufA;
            u16x8* wnxt = (p & 1) ? wbufA : wbufB;

            if (p + 1 < NCONN) loadW(p + 1, wnxt);  // prefetch next conn

            // bias (L2-resident; consumed post-MFMA, latency hidden)
            const float* bp = bs + c * DD + l15;
            float bv0 = bp[0], bv1 = bp[16], bv2 = bp[32], bv3 = bp[48];
            float bvv[4] = {bv0, bv1, bv2, bv3};

            __builtin_amdgcn_s_setprio(1);
#pragma unroll
            for (int t = 0; t < 4; ++t) {
                const f32x4 b4 = {bvv[t], bvv[t], bvv[t], bvv[t]};
#pragma unroll
                for (int rt = 0; rt < 2; ++rt) {
                    f32x4 C = acc[rt][t];
                    C = __builtin_amdgcn_mfma_f32_16x16x32_bf16(
                            afrag[i][rt][0], __builtin_bit_cast(bf16x8, wcur[t * 2 + 0]), C, 0, 0, 0);
                    C = __builtin_amdgcn_mfma_f32_16x16x32_bf16(
                            afrag[i][rt][1], __builtin_bit_cast(bf16x8, wcur[t * 2 + 1]), C, 0, 0, 0);
                    acc[rt][t] = vmax4(C + b4, acc[rt][t]);
                }
            }
            __builtin_amdgcn_s_setprio(0);
        }

        if (j < 7) {
            // D-layout -> A-frag layout via wave-private 2KB LDS bounce.
            // XOR-swizzle keeps ds reads/writes low-conflict; compiler inserts
            // the lgkm waits from visible dependencies (plain C, no asm).
#pragma unroll
            for (int rt = 0; rt < 2; ++rt) {
#pragma unroll
                for (int t = 0; t < 4; ++t) {
                    const int n = t * 16 + l15;
#pragma unroll
                    for (int q = 0; q < 4; ++q) {
                        const int mr = kg * 4 + q;
                        myB[mr * DD + (n ^ ((mr & 7) << 3))] = f2bfu(acc[rt][t][q]);
                    }
                }
#pragma unroll
                for (int s = 0; s < 2; ++s) {
                    u16x8 ra = *reinterpret_cast<const u16x8*>(
                        &myB[l15 * DD + ((s * 32 + kg * 8) ^ ((l15 & 7) << 3))]);
                    afrag[j][rt][s] = __builtin_bit_cast(bf16x8, ra);
                }
            }
        } else {
            float* orow = out + rowbase * DD;
#pragma unroll
            for (int rt = 0; rt < 2; ++rt)
#pragma unroll
                for (int t = 0; t < 4; ++t)
#pragma unroll
                    for (int q = 0; q < 4; ++q)
                        orow[(rt * 16 + kg * 4 + q) * DD + t * 16 + l15] = acc[rt][t][q];
        }
    }
}

extern "C" void kernel_launch(void* const* d_in, const int* in_sizes, int n_in,
                              void* d_out, int out_size, void* d_ws, size_t ws_size,
                              hipStream_t stream) {
    const float* x  = (const float*)d_in[0];
    const float* Ws = (const float*)d_in[1];
    const float* bs = (const float*)d_in[2];
    float* out = (float*)d_out;

    const int nrows = in_sizes[0] / DD;            // 262144
    const int grid  = nrows / ROWS_PER_BLOCK;      // 2048

    const size_t wbf_bytes = (size_t)NCONN * MAT_ELEMS * sizeof(unsigned short);
    if (ws_size >= wbf_bytes) {
        unsigned short* wbf = (unsigned short*)d_ws;
        wconv_kernel<<<(NCONN * 512 + 255) / 256, 256, 0, stream>>>(Ws, wbf);
        dag_kernel<true><<<grid, THREADS, 0, stream>>>(x, Ws, wbf, bs, out);
    } else {
        dag_kernel<false><<<grid, THREADS, 0, stream>>>(x, Ws, nullptr, bs, out);
    }
}

// Round 7
// 108.965 us; speedup vs baseline: 2.0803x; 2.0803x over previous
//
#include <hip/hip_runtime.h>

// DAG MLP: L=8 layers, D=64, B=262144, 28 all-to-all forward connections.
// outs[j] += relu(outs[i] @ W_c^T + b_c), output = outs[7].
// v7 = v5 data path with 2-WAVE BLOCKS for 4 independent barrier domains/CU:
//   - 128 threads (2 waves x 32 rows), grid 4096, LDS 36KB -> 4 blocks/CU
//   - 4-slot LDS ring, pair barriers (__syncthreads once per 2 conns)
//   - weights via global_load_lds(16B) from pre-swizzled bf16 image in d_ws
//   - bias in register ping-pong, loaded BEFORE glls (FIFO: bias waits never
//     drain outstanding gll prefetches)
//   - accumulation rides MFMA C: C_in=acc; acc = max(D + bias, acc)
//     == acc + relu(S + bias)  (exact in f32)

#define DD 64
#define NCONN 28
#define THREADS 128
#define ROWS_PER_WAVE 32
#define ROWS_PER_BLOCK 64      // 2 waves * 32 rows
#define MAT_ELEMS 4096         // 64*64

typedef __bf16 bf16x8 __attribute__((ext_vector_type(8)));
typedef float f32x4 __attribute__((ext_vector_type(4)));
typedef unsigned short u16x8 __attribute__((ext_vector_type(8)));

// c(i->j) = OFFS[i] + (j-i-1); CONN[p] = connection at compute position p
// (phases j=1..7, sources i ascending within phase).
__device__ constexpr int OFFS[7] = {0, 7, 13, 18, 22, 25, 27};
__device__ constexpr int CONN[28] = {0, 1,7, 2,8,13, 3,9,14,18, 4,10,15,19,22,
                                     5,11,16,20,23,25, 6,12,17,21,24,26,27};

__device__ __forceinline__ unsigned short f2bfu(float f) {
    return __builtin_bit_cast(unsigned short, (__bf16)f);
}

__device__ __forceinline__ f32x4 vmax4(f32x4 a, f32x4 b) {
#if __has_builtin(__builtin_elementwise_max)
    return __builtin_elementwise_max(a, b);
#else
    f32x4 r;
    r[0] = fmaxf(a[0], b[0]); r[1] = fmaxf(a[1], b[1]);
    r[2] = fmaxf(a[2], b[2]); r[3] = fmaxf(a[3], b[3]);
    return r;
#endif
}

__device__ __forceinline__ void gll16(const unsigned short* g, unsigned short* l) {
    __builtin_amdgcn_global_load_lds(
        (const __attribute__((address_space(1))) unsigned int*)g,
        (__attribute__((address_space(3))) unsigned int*)l, 16, 0, 0);
}

// fp32 W -> bf16 PRE-SWIZZLED image: img[c][r*64 + (k ^ ((r&7)<<3))] = W[c][r][k]
// so a lane-linear global_load_lds copy reproduces the swizzled LDS layout.
__global__ void wconv_kernel(const float* __restrict__ w,
                             unsigned short* __restrict__ o) {
    int i = blockIdx.x * blockDim.x + threadIdx.x;   // one 8-elem chunk each
    if (i >= NCONN * 512) return;
    int conn = i >> 9;
    int within = i & 511;
    int r  = within >> 3;
    int k0 = (within & 7) << 3;
    const float* src = w + conn * MAT_ELEMS + r * DD + k0;
    float4 v0 = *reinterpret_cast<const float4*>(src);
    float4 v1 = *reinterpret_cast<const float4*>(src + 4);
    u16x8 d;
    d[0] = f2bfu(v0.x); d[1] = f2bfu(v0.y); d[2] = f2bfu(v0.z); d[3] = f2bfu(v0.w);
    d[4] = f2bfu(v1.x); d[5] = f2bfu(v1.y); d[6] = f2bfu(v1.z); d[7] = f2bfu(v1.w);
    *reinterpret_cast<u16x8*>(o + conn * MAT_ELEMS + r * DD + (k0 ^ ((r & 7) << 3))) = d;
}

template <bool GLL>
__global__ __launch_bounds__(THREADS, 2)
void dag_kernel(const float* __restrict__ x,
                const float* __restrict__ Wf,
                const unsigned short* __restrict__ Wimg,
                const float* __restrict__ bs,
                float* __restrict__ out) {
    __shared__ __align__(16) unsigned short ring[4 * MAT_ELEMS];    // 32 KB
    __shared__ __align__(16) unsigned short sB[2 * 1024];           //  4 KB bounce

    const int tid  = threadIdx.x;
    const int lane = tid & 63;
    const int wv   = tid >> 6;
    const int l15  = lane & 15;
    const int kg   = lane >> 4;

    const long rowbase = (long)blockIdx.x * ROWS_PER_BLOCK + wv * ROWS_PER_WAVE;

    // ---- x -> afrag[0] ----
    bf16x8 afrag[7][2][2];   // [src layer][rowtile][kstep]
#pragma unroll
    for (int rt = 0; rt < 2; ++rt) {
        const float* xr = x + (rowbase + rt * 16 + l15) * DD;
#pragma unroll
        for (int s = 0; s < 2; ++s) {
            float4 v0 = *reinterpret_cast<const float4*>(xr + s * 32 + kg * 8);
            float4 v1 = *reinterpret_cast<const float4*>(xr + s * 32 + kg * 8 + 4);
            bf16x8 f;
            f[0] = (__bf16)v0.x; f[1] = (__bf16)v0.y; f[2] = (__bf16)v0.z; f[3] = (__bf16)v0.w;
            f[4] = (__bf16)v1.x; f[5] = (__bf16)v1.y; f[6] = (__bf16)v1.z; f[7] = (__bf16)v1.w;
            afrag[0][rt][s] = f;
        }
    }

    // Bias ping-pong: breg[pair parity][conn in pair][t]; indices fold to
    // constants in the fully-unrolled loop.
    float breg[2][2][4];
    auto loadBias = [&](int p) {
        const float* bp = bs + CONN[p] * DD + l15;
        float* b = breg[(p >> 1) & 1][p & 1];
        b[0] = bp[0]; b[1] = bp[16]; b[2] = bp[32]; b[3] = bp[48];
    };

    auto stage_gll = [&](int p) {
        const unsigned short* src = Wimg + CONN[p] * MAT_ELEMS + lane * 8;
        unsigned short* dst = ring + (p & 3) * MAT_ELEMS + lane * 8;
#pragma unroll
        for (int h = 0; h < 4; ++h) {
            const int off = (wv * 4 + h) * 512;
            gll16(src + off, dst + off);
        }
    };
    auto stage_direct = [&](int p) {   // fallback: fp32 -> bf16 reg staging
        const float* wp = Wf + CONN[p] * MAT_ELEMS;
#pragma unroll
        for (int h = 0; h < 4; ++h) {
            const int e0 = h * 1024 + tid * 8;
            float4 a0 = *reinterpret_cast<const float4*>(wp + e0);
            float4 a1 = *reinterpret_cast<const float4*>(wp + e0 + 4);
            u16x8 d;
            d[0] = f2bfu(a0.x); d[1] = f2bfu(a0.y); d[2] = f2bfu(a0.z); d[3] = f2bfu(a0.w);
            d[4] = f2bfu(a1.x); d[5] = f2bfu(a1.y); d[6] = f2bfu(a1.z); d[7] = f2bfu(a1.w);
            const int r = e0 >> 6, k0 = e0 & 63;
            *reinterpret_cast<u16x8*>(ring + (p & 3) * MAT_ELEMS +
                                      r * DD + (k0 ^ ((r & 7) << 3))) = d;
        }
    };

    loadBias(0); loadBias(1);
    if constexpr (GLL) { stage_gll(0); stage_gll(1); }
    __syncthreads();   // prologue glls drained; slots 0,1 ready

    unsigned short* myB = sB + wv * 1024;
    f32x4 acc[2][4];

#pragma unroll
    for (int j = 1; j <= 7; ++j) {
#pragma unroll
        for (int rt = 0; rt < 2; ++rt)
#pragma unroll
            for (int t = 0; t < 4; ++t) {
                acc[rt][t][0] = 0.f; acc[rt][t][1] = 0.f;
                acc[rt][t][2] = 0.f; acc[rt][t][3] = 0.f;
            }

#pragma unroll
        for (int i = 0; i < j; ++i) {
            const int p = j * (j - 1) / 2 + i;      // compute position 0..27

            if constexpr (GLL) {
                // pair schedule: barrier once per even p; bias loads issued
                // BEFORE glls so vmcnt waits on bias never drain the glls.
                if ((p & 1) == 0) {
                    if (p > 0) __syncthreads();   // slots p,p+1 ready; p-2,p-1 free
                    if (p + 2 < NCONN) { loadBias(p + 2); loadBias(p + 3); }
                    if (p + 2 < NCONN) { stage_gll(p + 2); stage_gll(p + 3); }
                }
            } else {
                __syncthreads();
                stage_direct(p);
                loadBias(p);
                __syncthreads();
            }

            const unsigned short* wsl = ring + (p & 3) * MAT_ELEMS;
            const float* bv = breg[(p >> 1) & 1][p & 1];
            __builtin_amdgcn_s_setprio(1);
#pragma unroll
            for (int t = 0; t < 4; ++t) {
                const int n  = t * 16 + l15;
                const int xo = (n & 7) << 3;
                u16x8 rw0 = *reinterpret_cast<const u16x8*>(wsl + n * DD + ((kg * 8) ^ xo));
                u16x8 rw1 = *reinterpret_cast<const u16x8*>(wsl + n * DD + ((32 + kg * 8) ^ xo));
                const f32x4 b4 = {bv[t], bv[t], bv[t], bv[t]};
#pragma unroll
                for (int rt = 0; rt < 2; ++rt) {
                    f32x4 C = acc[rt][t];
                    C = __builtin_amdgcn_mfma_f32_16x16x32_bf16(
                            afrag[i][rt][0], __builtin_bit_cast(bf16x8, rw0), C, 0, 0, 0);
                    C = __builtin_amdgcn_mfma_f32_16x16x32_bf16(
                            afrag[i][rt][1], __builtin_bit_cast(bf16x8, rw1), C, 0, 0, 0);
                    acc[rt][t] = vmax4(C + b4, acc[rt][t]);
                }
            }
            __builtin_amdgcn_s_setprio(0);
        }

        if (j < 7) {
            // D-layout -> A-frag layout via wave-private 2KB bounce (no barrier;
            // plain C so the compiler tracks the LDS dependency itself).
#pragma unroll
            for (int rt = 0; rt < 2; ++rt) {
#pragma unroll
                for (int t = 0; t < 4; ++t) {
                    const int n = t * 16 + l15;
#pragma unroll
                    for (int q = 0; q < 4; ++q) {
                        const int mr = kg * 4 + q;
                        myB[mr * DD + (n ^ ((mr & 7) << 3))] = f2bfu(acc[rt][t][q]);
                    }
                }
#pragma unroll
                for (int s = 0; s < 2; ++s) {
                    u16x8 ra = *reinterpret_cast<const u16x8*>(
                        &myB[l15 * DD + ((s * 32 + kg * 8) ^ ((l15 & 7) << 3))]);
                    afrag[j][rt][s] = __builtin_bit_cast(bf16x8, ra);
                }
            }
        } else {
            float* orow = out + rowbase * DD;
#pragma unroll
            for (int rt = 0; rt < 2; ++rt)
#pragma unroll
                for (int t = 0; t < 4; ++t)
#pragma unroll
                    for (int q = 0; q < 4; ++q)
                        orow[(rt * 16 + kg * 4 + q) * DD + t * 16 + l15] = acc[rt][t][q];
        }
    }
}

extern "C" void kernel_launch(void* const* d_in, const int* in_sizes, int n_in,
                              void* d_out, int out_size, void* d_ws, size_t ws_size,
                              hipStream_t stream) {
    const float* x  = (const float*)d_in[0];
    const float* Ws = (const float*)d_in[1];
    const float* bs = (const float*)d_in[2];
    float* out = (float*)d_out;

    const int nrows = in_sizes[0] / DD;            // 262144
    const int grid  = nrows / ROWS_PER_BLOCK;      // 4096

    const size_t wbf_bytes = (size_t)NCONN * MAT_ELEMS * sizeof(unsigned short);
    if (ws_size >= wbf_bytes) {
        unsigned short* wbf = (unsigned short*)d_ws;
        wconv_kernel<<<(NCONN * 512 + 255) / 256, 256, 0, stream>>>(Ws, wbf);
        dag_kernel<true><<<grid, THREADS, 0, stream>>>(x, Ws, wbf, bs, out);
    } else {
        dag_kernel<false><<<grid, THREADS, 0, stream>>>(x, Ws, nullptr, bs, out);
    }
}

// Round 8
// 102.387 us; speedup vs baseline: 2.2140x; 1.0642x over previous
//
#include <hip/hip_runtime.h>

// DAG MLP: L=8 layers, D=64, B=262144, 28 all-to-all forward connections.
// outs[j] += relu(outs[i] @ W_c^T + b_c), output = outs[7].
// v8: FEATURE-SPLIT WAVE PAIRS to cut per-wave registers -> 3 waves/SIMD.
//   - 4 waves/block = 2 pairs; each pair owns 32 batch rows; within a pair,
//     wave h in {0,1} computes output features h*32..h*32+31 of every conn.
//   - afrag (full K) unchanged; acc halves to 16 f32; W reads 4xb128/conn.
//   - per-phase D->A bounce via pair-shared LDS with an lgkm-only barrier
//     (does NOT drain vmcnt -> gll prefetches stay in flight).
//   - v5 schedule kept: 4-slot ring, pair __syncthreads, pre-swizzled bf16
//     W image in d_ws via global_load_lds(16B), bias in LDS, MFMA-carried
//     accumulation: C_in=acc; acc = max(D + bias, acc) == acc + relu(S+b).

#define DD 64
#define NCONN 28
#define THREADS 256
#define ROWS_PER_BLOCK 64      // 2 pairs * 32 rows
#define MAT_ELEMS 4096         // 64*64

typedef __bf16 bf16x8 __attribute__((ext_vector_type(8)));
typedef float f32x4 __attribute__((ext_vector_type(4)));
typedef unsigned short u16x8 __attribute__((ext_vector_type(8)));

// c(i->j) = OFFS[i] + (j-i-1); CONN[p] = connection at compute position p
// (phases j=1..7, sources i ascending within phase).
__device__ constexpr int OFFS[7] = {0, 7, 13, 18, 22, 25, 27};
__device__ constexpr int CONN[28] = {0, 1,7, 2,8,13, 3,9,14,18, 4,10,15,19,22,
                                     5,11,16,20,23,25, 6,12,17,21,24,26,27};

__device__ __forceinline__ unsigned short f2bfu(float f) {
    return __builtin_bit_cast(unsigned short, (__bf16)f);
}

__device__ __forceinline__ f32x4 vmax4(f32x4 a, f32x4 b) {
#if __has_builtin(__builtin_elementwise_max)
    return __builtin_elementwise_max(a, b);
#else
    f32x4 r;
    r[0] = fmaxf(a[0], b[0]); r[1] = fmaxf(a[1], b[1]);
    r[2] = fmaxf(a[2], b[2]); r[3] = fmaxf(a[3], b[3]);
    return r;
#endif
}

__device__ __forceinline__ void gll16(const unsigned short* g, unsigned short* l) {
    __builtin_amdgcn_global_load_lds(
        (const __attribute__((address_space(1))) unsigned int*)g,
        (__attribute__((address_space(3))) unsigned int*)l, 16, 0, 0);
}

// LDS-only barrier: drains lgkm (LDS writes visible) but NOT vmcnt, so
// outstanding global_load_lds prefetches survive. Memory-clobber asm on both
// sides pins LDS reads/writes to their side of the barrier.
__device__ __forceinline__ void lds_barrier() {
    asm volatile("s_waitcnt lgkmcnt(0)" ::: "memory");
    __builtin_amdgcn_s_barrier();
    asm volatile("" ::: "memory");
}

// fp32 W -> bf16 PRE-SWIZZLED image: img[c][r*64 + (k ^ ((r&7)<<3))] = W[c][r][k]
// so a lane-linear global_load_lds copy reproduces the swizzled LDS layout.
__global__ void wconv_kernel(const float* __restrict__ w,
                             unsigned short* __restrict__ o) {
    int i = blockIdx.x * blockDim.x + threadIdx.x;   // one 8-elem chunk each
    if (i >= NCONN * 512) return;
    int conn = i >> 9;
    int within = i & 511;
    int r  = within >> 3;
    int k0 = (within & 7) << 3;
    const float* src = w + conn * MAT_ELEMS + r * DD + k0;
    float4 v0 = *reinterpret_cast<const float4*>(src);
    float4 v1 = *reinterpret_cast<const float4*>(src + 4);
    u16x8 d;
    d[0] = f2bfu(v0.x); d[1] = f2bfu(v0.y); d[2] = f2bfu(v0.z); d[3] = f2bfu(v0.w);
    d[4] = f2bfu(v1.x); d[5] = f2bfu(v1.y); d[6] = f2bfu(v1.z); d[7] = f2bfu(v1.w);
    *reinterpret_cast<u16x8*>(o + conn * MAT_ELEMS + r * DD + (k0 ^ ((r & 7) << 3))) = d;
}

template <bool GLL>
__global__ __launch_bounds__(THREADS, 3)
void dag_kernel(const float* __restrict__ x,
                const float* __restrict__ Wf,
                const unsigned short* __restrict__ Wimg,
                const float* __restrict__ bs,
                float* __restrict__ out) {
    __shared__ __align__(16) unsigned short ring[4 * MAT_ELEMS];    // 32 KB
    __shared__ __align__(16) unsigned short sB[2 * 2048];           //  8 KB: 4 KB/pair
    __shared__ __align__(16) float sBias[NCONN * DD];               //  7 KB

    const int tid  = threadIdx.x;
    const int lane = tid & 63;
    const int wv   = tid >> 6;
    const int pair = wv >> 1;     // 0,1
    const int h    = wv & 1;      // feature half
    const int l15  = lane & 15;
    const int kg   = lane >> 4;

    const long rowbase = (long)blockIdx.x * ROWS_PER_BLOCK + pair * 32;

    // ---- prologue: bias -> LDS, x -> afrag[0] ----
    for (int idx = tid; idx < NCONN * DD / 4; idx += THREADS)
        reinterpret_cast<float4*>(sBias)[idx] = reinterpret_cast<const float4*>(bs)[idx];

    bf16x8 afrag[7][2][2];   // [src layer][row tile][k step]; rows rt*16+l15, k s*32+kg*8
#pragma unroll
    for (int rt = 0; rt < 2; ++rt) {
        const float* xr = x + (rowbase + rt * 16 + l15) * DD;
#pragma unroll
        for (int s = 0; s < 2; ++s) {
            float4 v0 = *reinterpret_cast<const float4*>(xr + s * 32 + kg * 8);
            float4 v1 = *reinterpret_cast<const float4*>(xr + s * 32 + kg * 8 + 4);
            bf16x8 f;
            f[0] = (__bf16)v0.x; f[1] = (__bf16)v0.y; f[2] = (__bf16)v0.z; f[3] = (__bf16)v0.w;
            f[4] = (__bf16)v1.x; f[5] = (__bf16)v1.y; f[6] = (__bf16)v1.z; f[7] = (__bf16)v1.w;
            afrag[0][rt][s] = f;
        }
    }

    auto stage_gll = [&](int p) {
        const unsigned short* src = Wimg + CONN[p] * MAT_ELEMS + wv * 512 + lane * 8;
        unsigned short* dst = ring + (p & 3) * MAT_ELEMS + wv * 512;
#pragma unroll
        for (int hh = 0; hh < 2; ++hh)
            gll16(src + hh * 2048, dst + hh * 2048);
    };
    auto stage_direct = [&](int p) {   // fallback: fp32 -> bf16 reg staging
        const float* wp = Wf + CONN[p] * MAT_ELEMS;
#pragma unroll
        for (int hh = 0; hh < 2; ++hh) {
            const int e0 = hh * 2048 + tid * 8;
            float4 a0 = *reinterpret_cast<const float4*>(wp + e0);
            float4 a1 = *reinterpret_cast<const float4*>(wp + e0 + 4);
            u16x8 d;
            d[0] = f2bfu(a0.x); d[1] = f2bfu(a0.y); d[2] = f2bfu(a0.z); d[3] = f2bfu(a0.w);
            d[4] = f2bfu(a1.x); d[5] = f2bfu(a1.y); d[6] = f2bfu(a1.z); d[7] = f2bfu(a1.w);
            const int r = e0 >> 6, k0 = e0 & 63;
            *reinterpret_cast<u16x8*>(ring + (p & 3) * MAT_ELEMS +
                                      r * DD + (k0 ^ ((r & 7) << 3))) = d;
        }
    };

    if constexpr (GLL) { stage_gll(0); stage_gll(1); }
    __syncthreads();   // bias published, prologue glls drained; slots 0,1 ready

    unsigned short* myPB = sB + pair * 2048;   // pair-shared 32x64 bf16 bounce
    f32x4 acc[2][2];   // [row tile][feat tile within half]; n = h*32 + t*16 + l15

#pragma unroll
    for (int j = 1; j <= 7; ++j) {
#pragma unroll
        for (int rt = 0; rt < 2; ++rt)
#pragma unroll
            for (int t = 0; t < 2; ++t) {
                acc[rt][t][0] = 0.f; acc[rt][t][1] = 0.f;
                acc[rt][t][2] = 0.f; acc[rt][t][3] = 0.f;
            }

#pragma unroll
        for (int i = 0; i < j; ++i) {
            const int p = j * (j - 1) / 2 + i;      // compute position 0..27
            const int c = OFFS[i] + (j - i - 1);    // connection index

            if constexpr (GLL) {
                // pair-of-conns schedule: __syncthreads once per even p
                // (implicit vmcnt(0) drains glls staged at p-2 -> slots ready)
                if ((p & 1) == 0) {
                    if (p > 0) __syncthreads();
                    if (p + 2 < NCONN) { stage_gll(p + 2); stage_gll(p + 3); }
                }
            } else {
                __syncthreads();
                stage_direct(p);
                __syncthreads();
            }

            const unsigned short* wsl = ring + (p & 3) * MAT_ELEMS;
            __builtin_amdgcn_s_setprio(1);
#pragma unroll
            for (int t = 0; t < 2; ++t) {
                const int n  = h * 32 + t * 16 + l15;   // this wave's feature
                const int xo = (n & 7) << 3;
                u16x8 rw0 = *reinterpret_cast<const u16x8*>(wsl + n * DD + ((kg * 8) ^ xo));
                u16x8 rw1 = *reinterpret_cast<const u16x8*>(wsl + n * DD + ((32 + kg * 8) ^ xo));
                const float bv = sBias[c * DD + n];
                const f32x4 b4 = {bv, bv, bv, bv};
#pragma unroll
                for (int rt = 0; rt < 2; ++rt) {
                    f32x4 C = acc[rt][t];
                    C = __builtin_amdgcn_mfma_f32_16x16x32_bf16(
                            afrag[i][rt][0], __builtin_bit_cast(bf16x8, rw0), C, 0, 0, 0);
                    C = __builtin_amdgcn_mfma_f32_16x16x32_bf16(
                            afrag[i][rt][1], __builtin_bit_cast(bf16x8, rw1), C, 0, 0, 0);
                    acc[rt][t] = vmax4(C + b4, acc[rt][t]);
                }
            }
            __builtin_amdgcn_s_setprio(0);
        }

        if (j < 7) {
            // Pair bounce: each wave writes its feature half of D (bf16,
            // XOR-swizzled); lgkm-only barrier; both waves read full rows.
#pragma unroll
            for (int rt = 0; rt < 2; ++rt)
#pragma unroll
                for (int t = 0; t < 2; ++t) {
                    const int f = h * 32 + t * 16 + l15;
#pragma unroll
                    for (int q = 0; q < 4; ++q) {
                        const int mr = rt * 16 + kg * 4 + q;
                        myPB[mr * DD + (f ^ ((mr & 7) << 3))] = f2bfu(acc[rt][t][q]);
                    }
                }
            lds_barrier();   // pair writes visible; vmcnt (glls) NOT drained
#pragma unroll
            for (int rt = 0; rt < 2; ++rt)
#pragma unroll
                for (int s = 0; s < 2; ++s) {
                    u16x8 ra = *reinterpret_cast<const u16x8*>(
                        &myPB[(rt * 16 + l15) * DD + ((s * 32 + kg * 8) ^ ((l15 & 7) << 3))]);
                    afrag[j][rt][s] = __builtin_bit_cast(bf16x8, ra);
                }
            lds_barrier();   // reads done before next phase's writes reuse myPB
        } else {
            float* orow = out + rowbase * DD;
#pragma unroll
            for (int rt = 0; rt < 2; ++rt)
#pragma unroll
                for (int t = 0; t < 2; ++t)
#pragma unroll
                    for (int q = 0; q < 4; ++q)
                        orow[(rt * 16 + kg * 4 + q) * DD + h * 32 + t * 16 + l15] =
                            acc[rt][t][q];
        }
    }
}

extern "C" void kernel_launch(void* const* d_in, const int* in_sizes, int n_in,
                              void* d_out, int out_size, void* d_ws, size_t ws_size,
                              hipStream_t stream) {
    const float* x  = (const float*)d_in[0];
    const float* Ws = (const float*)d_in[1];
    const float* bs = (const float*)d_in[2];
    float* out = (float*)d_out;

    const int nrows = in_sizes[0] / DD;            // 262144
    const int grid  = nrows / ROWS_PER_BLOCK;      // 4096

    const size_t wbf_bytes = (size_t)NCONN * MAT_ELEMS * sizeof(unsigned short);
    if (ws_size >= wbf_bytes) {
        unsigned short* wbf = (unsigned short*)d_ws;
        wconv_kernel<<<(NCONN * 512 + 255) / 256, 256, 0, stream>>>(Ws, wbf);
        dag_kernel<true><<<grid, THREADS, 0, stream>>>(x, Ws, wbf, bs, out);
    } else {
        dag_kernel<false><<<grid, THREADS, 0, stream>>>(x, Ws, nullptr, bs, out);
    }
}